// Round 17
// baseline (71.756 us; speedup 1.0000x reference)
//
#include <hip/hip_runtime.h>
#include <hip/hip_fp16.h>

#define TEX_H 256
#define TEX_W 256
#define FCH 16
#define NPIX (8 * 256 * 256)
#define NCELL (256 * 256)

#define SQRT2_F 1.41421356237f
// Interior weights (grid anchored at u-2 => du,dv exactly in {0,1,2};
// d=2 slots fail w>0.1, leaving the 3x3 with constant weights):
#define W_EDGE   0.24311673443f   // exp(-sqrt(2))
#define W_DIAG   0.13533528324f   // exp(-2)

typedef float vf4 __attribute__((ext_vector_type(4)));

// ---- splat: 8 lanes per pixel; lane l owns channel pair (2l,2l+1); one
// packed fp16 atomic per lane into the pixel's center cell of replica
// (blockIdx & repmask). Blocks with equal (blockIdx&7) share an XCD under
// round-robin dispatch -> each replica's lines are single-XCD-owned, so the
// RMW can stay in that XCD's L2 (theory under test). Boundary pixels
// (~0.8%): exact fp32 path into shared strips (tiny traffic). ----
__global__ __launch_bounds__(256) void splat_kernel(
    const float*  __restrict__ f_map,
    const float2* __restrict__ uv_map,
    const float*  __restrict__ mask,
    __half2* __restrict__ halo,      // [nrepl][NCELL][8] half2
    float*   __restrict__ hcnt,      // [nrepl][NCELL]
    float*   __restrict__ dirc,      // [2048][16]
    float*   __restrict__ dirw,      // [2048]
    int repmask)
{
    int tid = blockIdx.x * 256 + threadIdx.x;
    int pix = tid >> 3;
    int l   = tid & 7;

    if (mask[pix] == 0.0f) return;

    float2 uv = uv_map[pix];
    float u = uv.x * 256.0f;
    float v = uv.y * 256.0f;

    if (u >= 2.0f && v >= 2.0f) {
        int rep  = blockIdx.x & repmask;
        size_t cell = (size_t)(rep) * NCELL + ((int)v) * 256 + (int)u;
        float2 fp = ((const float2*)f_map)[(size_t)pix * 8 + l]; // ch 2l,2l+1
        __half2 h = __floats2half2_rn(fp.x, fp.y);
        unsafeAtomicAdd(&halo[cell * 8 + l], h);
        if (l == 0) unsafeAtomicAdd(&hcnt[cell], 1.0f);
    } else {
        // Exact reference path; passing slots have ui<4 (u<2) or vi<4 (v<2).
        float fa = f_map[(size_t)pix * FCH + l];
        float fb = f_map[(size_t)pix * FCH + l + 8];
        float us = fmaxf(u - 2.0f, 0.0f);
        float vs = fmaxf(v - 2.0f, 0.0f);
        #pragma unroll
        for (int kv = 0; kv < 4; ++kv) {
            float vg = vs + (float)kv;
            int vi = (int)vg;
            float dvf = fabsf(vg - v);
            #pragma unroll
            for (int ku = 0; ku < 4; ++ku) {
                float ug = us + (float)ku;
                int ui = (int)ug;
                float duf = fabsf(ug - u);
                float w = expf(-sqrtf(duf * duf + dvf * dvf) * SQRT2_F);
                if (w > 0.1f && vi < TEX_H && ui < TEX_W) {
                    int cell = (ui < 4) ? (ui * 256 + vi)        // region 0 (u<2)
                                        : ((4 + vi) * 256 + ui); // region 1 (vi<4)
                    unsafeAtomicAdd(&dirc[(size_t)cell * FCH + l],     w * fa);
                    unsafeAtomicAdd(&dirc[(size_t)cell * FCH + l + 8], w * fb);
                    if (l == 0) unsafeAtomicAdd(&dirw[cell], w);
                }
            }
        }
    }
}

// ---- finalize: WG = 8x8 texel tile. Stage the 10x10 halo summed over all
// replicas into LDS (fp32 accumulation -> better precision than r15), 3x3
// const-weight conv, merge exact fp32 strips, normalize, NT-store 8 copies.
// Single kernel (r16's 4x split regressed). ----
__global__ __launch_bounds__(256) void finalize_kernel(
    const __half2* __restrict__ halo,
    const float*   __restrict__ hcnt,
    const float*   __restrict__ dirc,
    const float*   __restrict__ dirw,
    int nrepl,
    float* __restrict__ out)
{
    __shared__ float s_h[100][16];    // 10x10 cells x 16 ch fp32 = 6.4 KB
    __shared__ float s_n[100];

    int tile = blockIdx.x;                  // 32x32 tiles of 8x8
    int r0 = (tile >> 5) << 3;
    int c0 = (tile & 31) << 3;

    int i = threadIdx.x;
    if (i < 200) {                          // 2 threads per halo cell (16B half each)
        int cellIdx = i >> 1, part = i & 1;
        int hr = cellIdx / 10, hc = cellIdx - hr * 10;
        int gr = r0 + hr - 1, gc = c0 + hc - 1;
        bool inb = (gr >= 0) & (gr < 256) & (gc >= 0) & (gc < 256);
        float acc[8] = {0,0,0,0,0,0,0,0};
        float ncc = 0.0f;
        if (inb) {
            size_t gcell = (size_t)gr * 256 + gc;
            for (int r = 0; r < nrepl; ++r) {
                uint4 val = *(const uint4*)&halo[((size_t)r * NCELL + gcell) * 8 + part * 4];
                const __half2* hp = (const __half2*)&val;
                #pragma unroll
                for (int j = 0; j < 4; ++j) {
                    float2 f = __half22float2(hp[j]);
                    acc[j * 2 + 0] += f.x;
                    acc[j * 2 + 1] += f.y;
                }
                if (part == 0) ncc += hcnt[(size_t)r * NCELL + gcell];
            }
        }
        #pragma unroll
        for (int j = 0; j < 8; ++j) s_h[cellIdx][part * 8 + j] = acc[j];
        if (part == 0) s_n[cellIdx] = ncc;
    }
    __syncthreads();

    int tx = threadIdx.x >> 2;              // texel in tile 0..63
    int c4 = threadIdx.x & 3;               // float4 chunk 0..3
    int lr = tx >> 3, lc = tx & 7;
    int gr = r0 + lr, gc = c0 + lc;

    vf4 cs = {0.f, 0.f, 0.f, 0.f};
    float wsm = 0.0f;

    #pragma unroll
    for (int a = 0; a < 3; ++a) {
        #pragma unroll
        for (int b = 0; b < 3; ++b) {
            float w = (a == 1 && b == 1) ? 1.0f
                    : ((a == 1 || b == 1) ? W_EDGE : W_DIAG);
            int idx = (lr + a) * 10 + (lc + b);
            cs += w * *(const vf4*)&s_h[idx][c4 * 4];
            wsm += w * s_n[idx];
        }
    }

    // Boundary strip merge (exact fp32; region mapping matches splat).
    if (gc < 4) {
        int cell = gc * 256 + gr;
        cs += *(const vf4*)&dirc[(size_t)cell * FCH + c4 * 4];
        wsm += dirw[cell];
    } else if (gr < 4) {
        int cell = (4 + gr) * 256 + gc;
        cs += *(const vf4*)&dirc[(size_t)cell * FCH + c4 * 4];
        wsm += dirw[cell];
    }

    float s = (wsm > 0.01f) ? (1.0f / (wsm + 0.001f)) : 0.0f;
    cs *= s;

    size_t base = ((size_t)gr * 256 + gc) * FCH + c4 * 4;
    #pragma unroll
    for (int b = 0; b < 8; ++b) {
        __builtin_nontemporal_store(cs, (vf4*)&out[(size_t)b * (256 * 256 * FCH) + base]);
    }
}

extern "C" void kernel_launch(void* const* d_in, const int* in_sizes, int n_in,
                              void* d_out, int out_size, void* d_ws, size_t ws_size,
                              hipStream_t stream) {
    const float*  f_map  = (const float*)d_in[0];
    const float2* uv_map = (const float2*)d_in[1];
    const float*  mask   = (const float*)d_in[2];
    float* out = (float*)d_out;
    char*  wsb = (char*)d_ws;

    const size_t STRIP_BYTES = 2048 * 16 * 4 + 2048 * 4;       // dirc + dirw
    // per-replica: halo 32B/cell + count 4B/cell
    int nrepl = 8;
    while (nrepl > 1 &&
           (size_t)nrepl * NCELL * 36 + STRIP_BYTES > ws_size) nrepl >>= 1;

    size_t halo_bytes = (size_t)nrepl * NCELL * 32;
    size_t hcnt_bytes = (size_t)nrepl * NCELL * 4;
    __half2* halo = (__half2*)wsb;
    float*   hcnt = (float*)(wsb + halo_bytes);
    float*   dirc = (float*)(wsb + halo_bytes + hcnt_bytes);
    float*   dirw = (float*)(wsb + halo_bytes + hcnt_bytes + 2048 * 16 * 4);

    (void)hipMemsetAsync(wsb, 0, halo_bytes + hcnt_bytes + STRIP_BYTES, stream);

    splat_kernel<<<(NPIX * 8) / 256, 256, 0, stream>>>(
        f_map, uv_map, mask, halo, hcnt, dirc, dirw, nrepl - 1);
    finalize_kernel<<<1024, 256, 0, stream>>>(halo, hcnt, dirc, dirw, nrepl, out);
}

// Round 18
// 62.050 us; speedup vs baseline: 1.1564x; 1.1564x over previous
//
#include <hip/hip_runtime.h>
#include <hip/hip_fp16.h>

#define TEX_H 256
#define TEX_W 256
#define FCH 16
#define NPIX (8 * 256 * 256)
#define NCELL (256 * 256)

#define SQRT2_F 1.41421356237f
// Interior weights (grid anchored at u-2 => du,dv exactly in {0,1,2};
// d=2 slots fail w>0.1, leaving the 3x3 with constant weights):
#define W_EDGE   0.24311673443f   // exp(-sqrt(2))
#define W_DIAG   0.13533528324f   // exp(-2)

typedef float vf4 __attribute__((ext_vector_type(4)));

// ws layout (bytes). Halo cell = 64 B (ONE cache line): halves 0-15 = fp16
// channel sums (sector 0), half 16 = fp16 count (sector 1), rest padding.
// One pixel touches ONE scattered line (vs 2 in r10/r15) — the line-touch
// invariant (516k lines / 44.5us = 740 GB/s ~ observed BW) predicts ~2x.
//  halo   [NCELL][16] __half2  @ 0          (4,194,304 B)
//  dir_c  [2048][16]  float    @ 4,194,304  (  131,072 B)  boundary strips
//  dir_w  [2048]      float    @ 4,325,376  (    8,192 B)
#define HALO_OFF   0
#define DIR_C_OFF  (NCELL * 64)
#define DIR_W_OFF  (DIR_C_OFF + 2048 * 16 * 4)
#define ZERO_BYTES (DIR_W_OFF + 2048 * 4)

// ---- splat: 8 lanes per pixel; lane l owns channel pair (2l,2l+1); one
// packed fp16 atomic per lane; lane 0 adds the count into the SAME 64B line
// (byte 32). Boundary pixels (~0.8%): exact fp32 path into strips. ----
__global__ __launch_bounds__(256) void splat_kernel(
    const float*  __restrict__ f_map,
    const float2* __restrict__ uv_map,
    const float*  __restrict__ mask,
    char* __restrict__ wsb)
{
    __half2* halo = (__half2*)(wsb + HALO_OFF);   // cell stride = 16 half2 (64B)
    float*   dirc = (float*)  (wsb + DIR_C_OFF);
    float*   dirw = (float*)  (wsb + DIR_W_OFF);

    int tid = blockIdx.x * 256 + threadIdx.x;
    int pix = tid >> 3;
    int l   = tid & 7;

    if (mask[pix] == 0.0f) return;

    float2 uv = uv_map[pix];
    float u = uv.x * 256.0f;
    float v = uv.y * 256.0f;

    if (u >= 2.0f && v >= 2.0f) {
        int cell = ((int)v) * 256 + (int)u;          // uv<1 => indices <=255
        float2 fp = ((const float2*)f_map)[(size_t)pix * 8 + l]; // ch 2l,2l+1
        __half2 h = __floats2half2_rn(fp.x, fp.y);
        __half2* hp = halo + (size_t)cell * 16;
        unsafeAtomicAdd(&hp[l], h);
        if (l == 0) unsafeAtomicAdd(&hp[8], __floats2half2_rn(1.0f, 0.0f));
    } else {
        // Exact reference path; passing slots have ui<4 (u<2) or vi<4 (v<2).
        float fa = f_map[(size_t)pix * FCH + l];
        float fb = f_map[(size_t)pix * FCH + l + 8];
        float us = fmaxf(u - 2.0f, 0.0f);
        float vs = fmaxf(v - 2.0f, 0.0f);
        #pragma unroll
        for (int kv = 0; kv < 4; ++kv) {
            float vg = vs + (float)kv;
            int vi = (int)vg;
            float dvf = fabsf(vg - v);
            #pragma unroll
            for (int ku = 0; ku < 4; ++ku) {
                float ug = us + (float)ku;
                int ui = (int)ug;
                float duf = fabsf(ug - u);
                float w = expf(-sqrtf(duf * duf + dvf * dvf) * SQRT2_F);
                if (w > 0.1f && vi < TEX_H && ui < TEX_W) {
                    int cell = (ui < 4) ? (ui * 256 + vi)        // region 0 (u<2)
                                        : ((4 + vi) * 256 + ui); // region 1 (vi<4)
                    unsafeAtomicAdd(&dirc[(size_t)cell * FCH + l],     w * fa);
                    unsafeAtomicAdd(&dirc[(size_t)cell * FCH + l + 8], w * fb);
                    if (l == 0) unsafeAtomicAdd(&dirw[cell], w);
                }
            }
        }
    }
}

// ---- finalize: WG = 8x8 texel tile (r15 structure, proven 13us / absmax
// 0.0078). Stage the 10x10 halo into LDS once, 3x3 const-weight conv from
// LDS, merge exact fp32 strips, normalize, NT-store 8 broadcast copies. ----
__global__ __launch_bounds__(256) void finalize_kernel(
    const char* __restrict__ wsb,
    float* __restrict__ out)
{
    const __half2* halo = (const __half2*)(wsb + HALO_OFF);
    const float*   dirc = (const float*)  (wsb + DIR_C_OFF);
    const float*   dirw = (const float*)  (wsb + DIR_W_OFF);

    __shared__ __half2 s_h[100][8];   // 10x10 cells x 16 ch (fp16) = 3200 B
    __shared__ float   s_n[100];

    int tile = blockIdx.x;                  // 32x32 tiles of 8x8
    int r0 = (tile >> 5) << 3;
    int c0 = (tile & 31) << 3;

    int i = threadIdx.x;
    if (i < 200) {                          // 2 threads per halo cell
        int cellIdx = i >> 1, part = i & 1;
        int hr = cellIdx / 10, hc = cellIdx - hr * 10;
        int gr = r0 + hr - 1, gc = c0 + hc - 1;
        uint4 val = make_uint4(0, 0, 0, 0);
        bool inb = (gr >= 0) & (gr < 256) & (gc >= 0) & (gc < 256);
        size_t gcell = inb ? ((size_t)gr * 256 + gc) : 0;
        if (inb)
            val = *(const uint4*)(halo + gcell * 16 + part * 4);  // 16B of payload
        *(uint4*)&s_h[cellIdx][part * 4] = val;
        if (part == 0)
            s_n[cellIdx] = inb ? __low2float(halo[gcell * 16 + 8]) : 0.0f;
    }
    __syncthreads();

    int tx = threadIdx.x >> 2;              // texel in tile 0..63
    int c4 = threadIdx.x & 3;               // float4 chunk 0..3
    int lr = tx >> 3, lc = tx & 7;
    int gr = r0 + lr, gc = c0 + lc;

    vf4 cs = {0.f, 0.f, 0.f, 0.f};
    float wsm = 0.0f;

    #pragma unroll
    for (int a = 0; a < 3; ++a) {
        #pragma unroll
        for (int b = 0; b < 3; ++b) {
            float w = (a == 1 && b == 1) ? 1.0f
                    : ((a == 1 || b == 1) ? W_EDGE : W_DIAG);
            int idx = (lr + a) * 10 + (lc + b);
            float2 f0 = __half22float2(s_h[idx][c4 * 2 + 0]);
            float2 f1 = __half22float2(s_h[idx][c4 * 2 + 1]);
            cs.x += w * f0.x; cs.y += w * f0.y;
            cs.z += w * f1.x; cs.w += w * f1.y;
            wsm  += w * s_n[idx];
        }
    }

    // Boundary strip merge (exact fp32; region mapping matches splat).
    if (gc < 4) {
        int cell = gc * 256 + gr;
        cs += *(const vf4*)&dirc[(size_t)cell * FCH + c4 * 4];
        wsm += dirw[cell];
    } else if (gr < 4) {
        int cell = (4 + gr) * 256 + gc;
        cs += *(const vf4*)&dirc[(size_t)cell * FCH + c4 * 4];
        wsm += dirw[cell];
    }

    float s = (wsm > 0.01f) ? (1.0f / (wsm + 0.001f)) : 0.0f;
    cs *= s;

    size_t base = ((size_t)gr * 256 + gc) * FCH + c4 * 4;
    #pragma unroll
    for (int b = 0; b < 8; ++b) {
        __builtin_nontemporal_store(cs, (vf4*)&out[(size_t)b * (256 * 256 * FCH) + base]);
    }
}

extern "C" void kernel_launch(void* const* d_in, const int* in_sizes, int n_in,
                              void* d_out, int out_size, void* d_ws, size_t ws_size,
                              hipStream_t stream) {
    const float*  f_map  = (const float*)d_in[0];
    const float2* uv_map = (const float2*)d_in[1];
    const float*  mask   = (const float*)d_in[2];
    float* out = (float*)d_out;
    char*  wsb = (char*)d_ws;

    (void)hipMemsetAsync(wsb, 0, (size_t)ZERO_BYTES, stream);

    splat_kernel<<<(NPIX * 8) / 256, 256, 0, stream>>>(f_map, uv_map, mask, wsb);
    finalize_kernel<<<1024, 256, 0, stream>>>(wsb, out);
}